// Round 10
// baseline (220.941 us; speedup 1.0000x reference)
//
#include <hip/hip_runtime.h>
#include <hip/hip_bf16.h>

// Problem constants (fixed by the reference setup)
constexpr int   kB    = 2048;    // rows in feats
constexpr int   kC    = 256;     // feature dim
constexpr int   kG    = 128;     // group size = topk * num_instances
constexpr int   kKg   = 128;     // number of label groups
constexpr float kEps  = 1e-6f;
constexpr float kInvT = 20.0f;   // 1/0.05

constexpr int kNA = kB  * kC;    // 524288  feats elements
constexpr int kNB = kB * 8 * kC; // 4194304 feats_s elements
constexpr int kBlocksSim = kKg * (kB / 128);  // 2048

typedef short bf16x8 __attribute__((ext_vector_type(8)));   // 8 bf16 in 4 VGPRs
typedef float floatx4 __attribute__((ext_vector_type(4)));  // MFMA accumulator

__device__ __forceinline__ unsigned short bf16_rne(float x) {
    union { float f; unsigned int u; } c; c.f = x;
    unsigned int r = c.u + 0x7FFFu + ((c.u >> 16) & 1u);
    return (unsigned short)(r >> 16);
}

// Kernel 1: fp32 -> bf16 pre-convert (once), zero pos_e/neg_e + done counter.
__global__ __launch_bounds__(256) void convert_kernel(
    const float* __restrict__ feats,    // [2048,256] fp32
    const float* __restrict__ feats_s,  // [16384,256] fp32
    __hip_bfloat16* __restrict__ fa,    // [2048,256] bf16 out
    __hip_bfloat16* __restrict__ fb,    // [16384,256] bf16 out
    float* __restrict__ zero_area)      // pos[2048] | neg[2048] | done
{
    int gid = blockIdx.x * 256 + threadIdx.x;
    if (gid <= 2 * kB) zero_area[gid] = 0.0f;   // 4097 words incl. counter

    size_t base = (size_t)gid * 8;
    const float* src; __hip_bfloat16* dst; size_t off;
    if (base < (size_t)kNA) { src = feats;   dst = fa; off = base; }
    else                    { src = feats_s; dst = fb; off = base - kNA; }
    float4 v0 = *(const float4*)(src + off);
    float4 v1 = *(const float4*)(src + off + 4);
    unsigned short u[8];
    u[0] = bf16_rne(v0.x); u[1] = bf16_rne(v0.y);
    u[2] = bf16_rne(v0.z); u[3] = bf16_rne(v0.w);
    u[4] = bf16_rne(v1.x); u[5] = bf16_rne(v1.y);
    u[6] = bf16_rne(v1.z); u[7] = bf16_rne(v1.w);
    *(uint4*)(dst + off) = *(const uint4*)u;
}

// Kernel 2: EXACT R7 sim structure — the best measured variant (no register
// prefetch: R5/R8/R9 all spilled it regardless of launch_bounds; lever is
// retired) — plus the R5/R8-correctness-proven fused finalize in the last
// finishing block (saves one launch + graph-node gap).
// 128x128 tile per block, 2x2 waves of 64x64 (4x4 acc), XOR-swizzled LDS
// p = q^(r&7) on 16B chunks both sides (0 conflicts, R6/R7-verified),
// lane-ascending coalesced global loads (R4 lesson).
__global__ __launch_bounds__(256) void sim_minmax_kernel(
    const __hip_bfloat16* __restrict__ fa,   // [2048,256] bf16
    const __hip_bfloat16* __restrict__ fb,   // [16384,256] bf16
    const int* __restrict__ labels,          // [2048]
    const int* __restrict__ labels_s,        // [16384]
    float* __restrict__ pos_e,               // [2048]
    float* __restrict__ neg_e,               // [2048]
    unsigned* __restrict__ done,             // completion counter
    float* __restrict__ out)                 // scalar loss
{
    const int group = blockIdx.x;        // 0..127
    const int row0  = blockIdx.y * 128;  // 0..2047 step 128
    const int n0    = group * kG;        // base row in Fs / labels_s

    __shared__ alignas(16) __hip_bfloat16 As[128 * 64];
    __shared__ alignas(16) __hip_bfloat16 Bs[128 * 64];
    __shared__ float rmin[128][2];
    __shared__ float rmax[128][2];
    __shared__ unsigned last_flag;

    const int t    = threadIdx.x;
    const int wave = t >> 6;
    const int lane = t & 63;
    const int l15  = lane & 15;
    const int quad = lane >> 4;
    const int wm   = wave >> 1;   // row half (0..1)
    const int wn   = wave & 1;    // col half (0..1)

    floatx4 acc[4][4];
#pragma unroll
    for (int mt = 0; mt < 4; mt++)
#pragma unroll
        for (int nt = 0; nt < 4; nt++)
            acc[mt][nt] = (floatx4){0.f, 0.f, 0.f, 0.f};

    for (int k0 = 0; k0 < kC; k0 += 64) {
        // Stage A and B: 1024 16B chunks each; c = t + 256*rep -> r = c>>3,
        // q = c&7. Global reads coalesced; LDS write at swizzled p = q^(r&7).
#pragma unroll
        for (int rep = 0; rep < 4; rep++) {
            int c = t + 256 * rep, r = c >> 3, q = c & 7;
            int p = (q ^ (r & 7)) * 8;
            uint4 va = *(const uint4*)(fa + (size_t)(row0 + r) * kC + k0 + q * 8);
            *(uint4*)(&As[r * 64 + p]) = va;
            uint4 vb = *(const uint4*)(fb + (size_t)(n0 + r) * kC + k0 + q * 8);
            *(uint4*)(&Bs[r * 64 + p]) = vb;
        }
        __syncthreads();

#pragma unroll
        for (int kk = 0; kk < 64; kk += 32) {
            const int kc = kk >> 3;                        // logical chunk base 0 or 4
            const int pc = ((kc + quad) ^ (l15 & 7)) * 8;  // swizzled offset (r&7 == l15&7)
            bf16x8 a[4], b[4];
#pragma unroll
            for (int mt = 0; mt < 4; mt++)
                a[mt] = *(const bf16x8*)(&As[(wm * 64 + mt * 16 + l15) * 64 + pc]);
#pragma unroll
            for (int nt = 0; nt < 4; nt++)
                b[nt] = *(const bf16x8*)(&Bs[(wn * 64 + nt * 16 + l15) * 64 + pc]);
#pragma unroll
            for (int mt = 0; mt < 4; mt++)
#pragma unroll
                for (int nt = 0; nt < 4; nt++)
                    acc[mt][nt] = __builtin_amdgcn_mfma_f32_16x16x32_bf16(
                        a[mt], b[nt], acc[mt][nt], 0, 0, 0);
        }
        __syncthreads();
    }

    // Per-row min/max over this wave's 64 columns.
    // D layout: col = lane&15, row = quad*4 + reg within each 16x16 tile.
#pragma unroll
    for (int mt = 0; mt < 4; mt++) {
#pragma unroll
        for (int reg = 0; reg < 4; reg++) {
            float vn = fminf(fminf(acc[mt][0][reg], acc[mt][1][reg]),
                             fminf(acc[mt][2][reg], acc[mt][3][reg]));
            float vx = fmaxf(fmaxf(acc[mt][0][reg], acc[mt][1][reg]),
                             fmaxf(acc[mt][2][reg], acc[mt][3][reg]));
#pragma unroll
            for (int s = 1; s < 16; s <<= 1) {
                vn = fminf(vn, __shfl_xor(vn, s, 64));
                vx = fmaxf(vx, __shfl_xor(vx, s, 64));
            }
            if (l15 == 0) {
                int r = wm * 64 + mt * 16 + quad * 4 + reg;
                rmin[r][wn] = vn;
                rmax[r][wn] = vx;
            }
        }
    }
    __syncthreads();

    if (t < 128) {
        float mn = fminf(rmin[t][0], rmin[t][1]);
        float mx = fmaxf(rmax[t][0], rmax[t][1]);
        int gb = row0 + t;
        if (labels[gb] == labels_s[n0]) {
            pos_e[gb] = __expf(mn * kInvT);            // unique writer per row
        } else {
            atomicAdd(&neg_e[gb], __expf(mx * kInvT));
        }
    }

    // ---- last-block finalize (device-scope fence + counter) ----
    __threadfence();          // release our pos/neg writes device-wide
    __syncthreads();
    if (t == 0) last_flag = atomicAdd(done, 1u);
    __syncthreads();
    if (last_flag == (unsigned)(kBlocksSim - 1)) {
        __threadfence();      // acquire all blocks' writes
        float s = 0.f;
        for (int r = t; r < kB; r += 256) {
            float p = pos_e[r];
            float n = neg_e[r];
            s += -__logf(p / (p + n + kEps) + kEps);
        }
#pragma unroll
        for (int sft = 32; sft > 0; sft >>= 1)
            s += __shfl_xor(s, sft, 64);
        if (lane == 0) rmin[wave][0] = s;
        __syncthreads();
        if (t == 0)
            out[0] = (rmin[0][0] + rmin[1][0] + rmin[2][0] + rmin[3][0]) / (float)kB;
    }
}

extern "C" void kernel_launch(void* const* d_in, const int* in_sizes, int n_in,
                              void* d_out, int out_size, void* d_ws, size_t ws_size,
                              hipStream_t stream) {
    (void)in_sizes; (void)n_in; (void)out_size; (void)ws_size;

    const float* feats    = (const float*)d_in[0];
    const float* feats_s  = (const float*)d_in[1];
    const int*   labels   = (const int*)d_in[2];
    const int*   labels_s = (const int*)d_in[3];
    // d_in[4] = topk (8), d_in[5] = num_instances (16) — fixed, hard-coded.

    // ws layout: pos[2048] f32 | neg[2048] f32 | done u32 | pad | fa 1MB | fb 8MB
    float*    pos_e = (float*)d_ws;
    float*    neg_e = pos_e + kB;
    unsigned* done  = (unsigned*)(neg_e + kB);
    __hip_bfloat16* fa = (__hip_bfloat16*)((char*)d_ws + 32768);
    __hip_bfloat16* fb = (__hip_bfloat16*)((char*)d_ws + 32768 + (size_t)kNA * 2);

    // convert: (kNA + kNB)/8 threads = 589824 -> 2304 blocks of 256
    convert_kernel<<<(kNA + kNB) / 8 / 256, 256, 0, stream>>>(
        feats, feats_s, fa, fb, pos_e);

    dim3 grid(kKg, kB / 128);   // 128 groups x 16 row-tiles = 2048 blocks
    sim_minmax_kernel<<<grid, 256, 0, stream>>>(
        fa, fb, labels, labels_s, pos_e, neg_e, done, (float*)d_out);
}

// Round 11
// 116.093 us; speedup vs baseline: 1.9031x; 1.9031x over previous
//
#include <hip/hip_runtime.h>
#include <hip/hip_bf16.h>

// Problem constants (fixed by the reference setup)
constexpr int   kB    = 2048;    // rows in feats
constexpr int   kC    = 256;     // feature dim
constexpr int   kG    = 128;     // group size = topk * num_instances
constexpr int   kKg   = 128;     // number of label groups
constexpr float kEps  = 1e-6f;
constexpr float kInvT = 20.0f;   // 1/0.05

constexpr int kNA = kB  * kC;    // 524288  feats elements
constexpr int kNB = kB * 8 * kC; // 4194304 feats_s elements

typedef short bf16x8 __attribute__((ext_vector_type(8)));   // 8 bf16 in 4 VGPRs
typedef float floatx4 __attribute__((ext_vector_type(4)));  // MFMA accumulator

__device__ __forceinline__ unsigned short bf16_rne(float x) {
    union { float f; unsigned int u; } c; c.f = x;
    unsigned int r = c.u + 0x7FFFu + ((c.u >> 16) & 1u);
    return (unsigned short)(r >> 16);
}

// Kernel 1: fp32 -> bf16 pre-convert (once), and zero pos_e/neg_e.
__global__ __launch_bounds__(256) void convert_kernel(
    const float* __restrict__ feats,    // [2048,256] fp32
    const float* __restrict__ feats_s,  // [16384,256] fp32
    __hip_bfloat16* __restrict__ fa,    // [2048,256] bf16 out
    __hip_bfloat16* __restrict__ fb,    // [16384,256] bf16 out
    float* __restrict__ zero_area)      // pos[2048], neg[2048]
{
    int gid = blockIdx.x * 256 + threadIdx.x;
    if (gid < 2 * kB) zero_area[gid] = 0.0f;

    size_t base = (size_t)gid * 8;
    const float* src; __hip_bfloat16* dst; size_t off;
    if (base < (size_t)kNA) { src = feats;   dst = fa; off = base; }
    else                    { src = feats_s; dst = fb; off = base - kNA; }
    float4 v0 = *(const float4*)(src + off);
    float4 v1 = *(const float4*)(src + off + 4);
    unsigned short u[8];
    u[0] = bf16_rne(v0.x); u[1] = bf16_rne(v0.y);
    u[2] = bf16_rne(v0.z); u[3] = bf16_rne(v0.w);
    u[4] = bf16_rne(v1.x); u[5] = bf16_rne(v1.y);
    u[6] = bf16_rne(v1.z); u[7] = bf16_rne(v1.w);
    *(uint4*)(dst + off) = *(const uint4*)u;
}

// Kernel 2: EXACT R7 sim kernel — the best measured variant (116.1 µs total).
// 128x128 tile per block, 2x2 waves of 64x64 (4x4 acc), XOR-swizzled LDS
// p = q^(r&7) on 16B chunks both sides (0 conflicts), lane-ascending
// coalesced global loads.
// Retired levers (do NOT reintroduce):
//  - register prefetch across the MFMA loop: spills at any launch_bounds
//    (R5/R8/R9: WRITE_SIZE 200+ MB scratch traffic).
//  - permuted-lane global_load_lds: breaks DMA coalescing (R4: 10x slower).
//  - fused finalize w/ per-block __threadfence: 2048 device-scope fences
//    serialize on L2 writeback, +120 µs (R10 isolated).
__global__ __launch_bounds__(256) void sim_minmax_kernel(
    const __hip_bfloat16* __restrict__ fa,   // [2048,256] bf16
    const __hip_bfloat16* __restrict__ fb,   // [16384,256] bf16
    const int* __restrict__ labels,          // [2048]
    const int* __restrict__ labels_s,        // [16384]
    float* __restrict__ pos_e,               // [2048]
    float* __restrict__ neg_e)               // [2048]
{
    const int group = blockIdx.x;        // 0..127
    const int row0  = blockIdx.y * 128;  // 0..2047 step 128
    const int n0    = group * kG;        // base row in Fs / labels_s

    __shared__ alignas(16) __hip_bfloat16 As[128 * 64];
    __shared__ alignas(16) __hip_bfloat16 Bs[128 * 64];
    __shared__ float rmin[128][2];
    __shared__ float rmax[128][2];

    const int t    = threadIdx.x;
    const int wave = t >> 6;
    const int lane = t & 63;
    const int l15  = lane & 15;
    const int quad = lane >> 4;
    const int wm   = wave >> 1;   // row half (0..1)
    const int wn   = wave & 1;    // col half (0..1)

    floatx4 acc[4][4];
#pragma unroll
    for (int mt = 0; mt < 4; mt++)
#pragma unroll
        for (int nt = 0; nt < 4; nt++)
            acc[mt][nt] = (floatx4){0.f, 0.f, 0.f, 0.f};

    for (int k0 = 0; k0 < kC; k0 += 64) {
        // Stage A and B: 1024 16B chunks each; c = t + 256*rep -> r = c>>3,
        // q = c&7. Global reads coalesced; LDS write at swizzled p = q^(r&7).
#pragma unroll
        for (int rep = 0; rep < 4; rep++) {
            int c = t + 256 * rep, r = c >> 3, q = c & 7;
            int p = (q ^ (r & 7)) * 8;
            uint4 va = *(const uint4*)(fa + (size_t)(row0 + r) * kC + k0 + q * 8);
            *(uint4*)(&As[r * 64 + p]) = va;
            uint4 vb = *(const uint4*)(fb + (size_t)(n0 + r) * kC + k0 + q * 8);
            *(uint4*)(&Bs[r * 64 + p]) = vb;
        }
        __syncthreads();

#pragma unroll
        for (int kk = 0; kk < 64; kk += 32) {
            const int kc = kk >> 3;                        // logical chunk base 0 or 4
            const int pc = ((kc + quad) ^ (l15 & 7)) * 8;  // swizzled offset (r&7 == l15&7)
            bf16x8 a[4], b[4];
#pragma unroll
            for (int mt = 0; mt < 4; mt++)
                a[mt] = *(const bf16x8*)(&As[(wm * 64 + mt * 16 + l15) * 64 + pc]);
#pragma unroll
            for (int nt = 0; nt < 4; nt++)
                b[nt] = *(const bf16x8*)(&Bs[(wn * 64 + nt * 16 + l15) * 64 + pc]);
#pragma unroll
            for (int mt = 0; mt < 4; mt++)
#pragma unroll
                for (int nt = 0; nt < 4; nt++)
                    acc[mt][nt] = __builtin_amdgcn_mfma_f32_16x16x32_bf16(
                        a[mt], b[nt], acc[mt][nt], 0, 0, 0);
        }
        __syncthreads();
    }

    // Per-row min/max over this wave's 64 columns.
    // D layout: col = lane&15, row = quad*4 + reg within each 16x16 tile.
#pragma unroll
    for (int mt = 0; mt < 4; mt++) {
#pragma unroll
        for (int reg = 0; reg < 4; reg++) {
            float vn = fminf(fminf(acc[mt][0][reg], acc[mt][1][reg]),
                             fminf(acc[mt][2][reg], acc[mt][3][reg]));
            float vx = fmaxf(fmaxf(acc[mt][0][reg], acc[mt][1][reg]),
                             fmaxf(acc[mt][2][reg], acc[mt][3][reg]));
#pragma unroll
            for (int s = 1; s < 16; s <<= 1) {
                vn = fminf(vn, __shfl_xor(vn, s, 64));
                vx = fmaxf(vx, __shfl_xor(vx, s, 64));
            }
            if (l15 == 0) {
                int r = wm * 64 + mt * 16 + quad * 4 + reg;
                rmin[r][wn] = vn;
                rmax[r][wn] = vx;
            }
        }
    }
    __syncthreads();

    if (t < 128) {
        float mn = fminf(rmin[t][0], rmin[t][1]);
        float mx = fmaxf(rmax[t][0], rmax[t][1]);
        int gb = row0 + t;
        if (labels[gb] == labels_s[n0]) {
            pos_e[gb] = __expf(mn * kInvT);            // unique writer per row
        } else {
            atomicAdd(&neg_e[gb], __expf(mx * kInvT));
        }
    }
}

// Kernel 3: per-row loss + mean over 2048 rows -> single fp32 scalar.
__global__ void finalize_kernel(const float* __restrict__ pos_e,
                                const float* __restrict__ neg_e,
                                float* __restrict__ out)
{
    __shared__ float red[256];
    float s = 0.f;
    for (int r = threadIdx.x; r < kB; r += 256) {
        float p = pos_e[r];
        float n = neg_e[r];
        s += -__logf(p / (p + n + kEps) + kEps);
    }
    red[threadIdx.x] = s;
    __syncthreads();
    for (int off = 128; off > 0; off >>= 1) {
        if (threadIdx.x < off) red[threadIdx.x] += red[threadIdx.x + off];
        __syncthreads();
    }
    if (threadIdx.x == 0) out[0] = red[0] / (float)kB;
}

extern "C" void kernel_launch(void* const* d_in, const int* in_sizes, int n_in,
                              void* d_out, int out_size, void* d_ws, size_t ws_size,
                              hipStream_t stream) {
    (void)in_sizes; (void)n_in; (void)out_size; (void)ws_size;

    const float* feats    = (const float*)d_in[0];
    const float* feats_s  = (const float*)d_in[1];
    const int*   labels   = (const int*)d_in[2];
    const int*   labels_s = (const int*)d_in[3];
    // d_in[4] = topk (8), d_in[5] = num_instances (16) — fixed, hard-coded.

    // ws layout: pos[2048] f32 | neg[2048] f32 | pad | fa 1MB | fb 8MB
    float* pos_e = (float*)d_ws;
    float* neg_e = pos_e + kB;
    __hip_bfloat16* fa = (__hip_bfloat16*)((char*)d_ws + 32768);
    __hip_bfloat16* fb = (__hip_bfloat16*)((char*)d_ws + 32768 + (size_t)kNA * 2);

    // convert: (kNA + kNB)/8 threads = 589824 -> 2304 blocks of 256
    convert_kernel<<<(kNA + kNB) / 8 / 256, 256, 0, stream>>>(
        feats, feats_s, fa, fb, pos_e);

    dim3 grid(kKg, kB / 128);   // 128 groups x 16 row-tiles = 2048 blocks
    sim_minmax_kernel<<<grid, 256, 0, stream>>>(
        fa, fb, labels, labels_s, pos_e, neg_e);
    finalize_kernel<<<1, 256, 0, stream>>>(pos_e, neg_e, (float*)d_out);
}